// Round 19
// baseline (1876.518 us; speedup 1.0000x reference)
//
#include <hip/hip_runtime.h>
#include <math.h>

#define Ee   200
#define Hh   128
#define G4   512          // 4*H
#define Kk   24
#define Bb   64
#define Tt   1024
#define HIDd 256
#define NEGf (-10000.0f)
#define PSTR 9            // partial-sum LDS stride (odd -> conflict-free)
#define CTC  128          // combo chunk length (8 chunks)

// ---------------------------------------------------------------------------
// K0: Wt[k][n] (k<200, n<1024): n<512 -> W_ih_f[n][k], else W_ih_b[n-512][k]
// ---------------------------------------------------------------------------
__global__ __launch_bounds__(256) void k_wt(const float* __restrict__ Wf,
                                            const float* __restrict__ Wb,
                                            float* __restrict__ Wt) {
    int idx = blockIdx.x * 256 + threadIdx.x;
    if (idx >= Ee * 1024) return;
    int k = idx >> 10, n = idx & 1023;
    Wt[idx] = (n < G4) ? Wf[n * Ee + k] : Wb[(n - G4) * Ee + k];
}

// ---------------------------------------------------------------------------
// GEMM tile body (proven r14/r16): BM=128 x BN=256, K=200, dbuf LDS,
//   one barrier per K-iter. tid<256 active; extra threads only hit barriers.
// ---------------------------------------------------------------------------
__device__ __forceinline__ void gemm_tile(const int* __restrict__ sent,
                                          const float* __restrict__ emb,
                                          const float* __restrict__ Wt,
                                          float* __restrict__ Uc,
                                          int m0, int n0, int tid,
                                          float* As, float* Bs, int* toks) {
    bool act = (tid < 256);
    int ty = (tid & 255) >> 4, tx = tid & 15;

    if (tid < 128) {
        int m = m0 + tid;
        toks[tid] = sent[(m & 63) * Tt + (m >> 6)];
    }
    __syncthreads();

    int am = tid & 127, ak4 = (tid >> 7) & 1;
    int brow = (tid >> 5) & 7, bc4 = tid & 31;

    const float* aptr = emb;
    const float* bptr = Wt;
    float4 av = make_float4(0, 0, 0, 0), bv0 = av, bv1 = av;
    float acc[8][16];
    if (act) {
        aptr = emb + (size_t)toks[am] * Ee + ak4 * 4;
        bptr = Wt + (size_t)brow * 1024 + n0 + bc4 * 4;
#pragma unroll
        for (int i = 0; i < 8; ++i)
#pragma unroll
            for (int j = 0; j < 16; ++j) acc[i][j] = 0.f;
        av  = *(const float4*)(aptr);
        bv0 = *(const float4*)(bptr);
        bv1 = *(const float4*)(bptr + 128);
    }

    const int NK = Ee / 8;                 // 25
    for (int k = 0; k < NK; ++k) {
        int cur = k & 1;
        if (act) {
            As[cur * 1024 + (ak4 * 4 + 0) * 128 + am] = av.x;
            As[cur * 1024 + (ak4 * 4 + 1) * 128 + am] = av.y;
            As[cur * 1024 + (ak4 * 4 + 2) * 128 + am] = av.z;
            As[cur * 1024 + (ak4 * 4 + 3) * 128 + am] = av.w;
            *(float4*)&Bs[cur * 2048 + brow * 256 + bc4 * 4]       = bv0;
            *(float4*)&Bs[cur * 2048 + brow * 256 + 128 + bc4 * 4] = bv1;
        }
        __syncthreads();                   // only barrier this iter

        if (act && k + 1 < NK) {
            int kc = (k + 1) * 8;
            av  = *(const float4*)(aptr + kc);
            bv0 = *(const float4*)(bptr + (size_t)kc * 1024);
            bv1 = *(const float4*)(bptr + (size_t)kc * 1024 + 128);
        }

        if (act) {
#pragma unroll
            for (int kk = 0; kk < 8; ++kk) {
                float a_[8], b_[16];
                *(float4*)&a_[0] = *(const float4*)&As[cur * 1024 + kk * 128 + ty * 8];
                *(float4*)&a_[4] = *(const float4*)&As[cur * 1024 + kk * 128 + ty * 8 + 4];
#pragma unroll
                for (int q = 0; q < 4; ++q)
                    *(float4*)&b_[4 * q] =
                        *(const float4*)&Bs[cur * 2048 + kk * 256 + tx * 4 + 64 * q];
#pragma unroll
                for (int i = 0; i < 8; ++i)
#pragma unroll
                    for (int j = 0; j < 16; ++j)
                        acc[i][j] = fmaf(a_[i], b_[j], acc[i][j]);
            }
        }
    }

    if (act) {
        int dd = n0 >> 9, ncol = n0 & 511;
        float* base = Uc + (size_t)dd * ((size_t)Tt * Bb * G4);
#pragma unroll
        for (int i = 0; i < 8; ++i) {
            float* dst = base + (size_t)(m0 + ty * 8 + i) * G4 + ncol + tx * 4;
#pragma unroll
            for (int q = 0; q < 4; ++q)
                *(float4*)(dst + 64 * q) =
                    make_float4(acc[i][4 * q], acc[i][4 * q + 1],
                                acc[i][4 * q + 2], acc[i][4 * q + 3]);
        }
    }
}

// ---------------------------------------------------------------------------
// LSTM chunk body — EXACT v2 math (proven 920us, conflicts=0), chunk-aware
//   unified indexing: u0 = d ? (Tt-1-c0T) : c0T.
// ---------------------------------------------------------------------------
__device__ __forceinline__ void lstm_chunk(const float* __restrict__ Uc,
                                           const float* __restrict__ Whh,
                                           const float* __restrict__ bih,
                                           const float* __restrict__ bhh,
                                           const float* __restrict__ h0v,
                                           const float* __restrict__ c0v,
                                           const float* __restrict__ Wout,
                                           float* __restrict__ hst,
                                           float* __restrict__ cst,
                                           float* __restrict__ pf,
                                           int b, int d, int c0T, int CT,
                                           int first, int unified, int tid,
                                           float* hsh, float* gsh, float* ps) {
    int lane = tid & 63, wv = tid >> 6;

    float bias = bih[tid] + bhh[tid];

    float w[8][16];
#pragma unroll
    for (int ri = 0; ri < 8; ++ri) {
        const float* wr = Whh + (size_t)(ri * 64 + lane) * Hh + wv * 16;
#pragma unroll
        for (int c4 = 0; c4 < 4; ++c4)
            *(float4*)&w[ri][c4 * 4] = *(const float4*)(wr + c4 * 4);
    }
    float wt[16];
    if (lane < Kk) {
        const float* wr = Wout + (size_t)lane * HIDd + d * Hh + wv * 16;
#pragma unroll
        for (int c4 = 0; c4 < 4; ++c4)
            *(float4*)&wt[c4 * 4] = *(const float4*)(wr + c4 * 4);
    }

    float cc = 0.f;
    if (tid < Hh) {
        int si = (d * Bb + b) * Hh + tid;
        hsh[tid] = first ? h0v[si] : hst[si];
        cc       = first ? c0v[si] : cst[si];
    }
    __syncthreads();

    const float* Ub = Uc + (size_t)d * ((size_t)(unified ? Tt : CT) * Bb * G4);
    int u0 = unified ? (d ? (Tt - 1 - c0T) : c0T) : 0;
    int us = unified ? (d ? -1 : 1) : 1;

    float ucur = Ub[(size_t)u0 * (Bb * G4) + b * G4 + tid];
    float unext = 0.f;

    for (int i = 0; i <= CT; ++i) {
        int last = (i == CT);
        float hv[16];
        *(float4*)&hv[0]  = *(const float4*)&hsh[wv * 16];
        *(float4*)&hv[4]  = *(const float4*)&hsh[wv * 16 + 4];
        *(float4*)&hv[8]  = *(const float4*)&hsh[wv * 16 + 8];
        *(float4*)&hv[12] = *(const float4*)&hsh[wv * 16 + 12];

        if (lane < Kk) {
            float s = 0.f;
#pragma unroll
            for (int c = 0; c < 16; ++c) s = fmaf(wt[c], hv[c], s);
            ps[(G4 + lane) * PSTR + wv] = s;
        }
        if (!last) {
#pragma unroll
            for (int ri = 0; ri < 8; ++ri) {
                float s = 0.f;
#pragma unroll
                for (int c = 0; c < 16; ++c) s = fmaf(w[ri][c], hv[c], s);
                ps[(ri * 64 + lane) * PSTR + wv] = s;
            }
            if (i + 1 < CT)
                unext = Ub[(size_t)(u0 + (i + 1) * us) * (Bb * G4) + b * G4 + tid];
        }
        __syncthreads();

        if (!last) {
            const float* pr = ps + (size_t)tid * PSTR;
            float s = ((pr[0] + pr[1]) + (pr[2] + pr[3])) +
                      ((pr[4] + pr[5]) + (pr[6] + pr[7]));
            s += ucur + bias;
            int gt = tid >> 7;                      // 0:i 1:f 2:g 3:o
            gsh[tid] = (gt == 2) ? tanhf(s) : 1.f / (1.f + expf(-s));
        }
        __syncthreads();

        if (!last && tid < Hh) {
            float gi = gsh[tid], gf = gsh[Hh + tid];
            float gg = gsh[2 * Hh + tid], go = gsh[3 * Hh + tid];
            cc = gf * cc + gi * gg;
            hsh[tid] = go * tanhf(cc);
        }
        if (tid >= 128 && tid < 128 + Kk && i >= 1) {
            int k = tid - 128;
            const float* pr = ps + (size_t)(G4 + k) * PSTR;
            float s = ((pr[0] + pr[1]) + (pr[2] + pr[3])) +
                      ((pr[4] + pr[5]) + (pr[6] + pr[7]));
            int tp = c0T + i - 1;
            int tg = d ? (Tt - 1 - tp) : tp;
            pf[((size_t)(d * Bb + b) * Tt + tg) * Kk + k] = s;
        }
        __syncthreads();
        ucur = unext;
    }

    if (tid < Hh) {
        int si = (d * Bb + b) * Hh + tid;
        hst[si] = hsh[tid];
        cst[si] = cc;
    }
}

// ---------------------------------------------------------------------------
// K1a: prologue GEMM for chunk 0 — small LDS (2 blocks/CU), full chip.
// ---------------------------------------------------------------------------
__global__ __launch_bounds__(256, 2) void k_gpro(const int* __restrict__ sent,
                                                 const float* __restrict__ emb,
                                                 const float* __restrict__ Wt,
                                                 float* __restrict__ Uc,
                                                 int nc0, int CT) {
    __shared__ float As[2048];
    __shared__ float Bs[4096];
    __shared__ int   toks[128];
    int gid = blockIdx.x;
    int band = gid / CT, rem = gid % CT;
    int ni = rem & 1, mi = rem >> 1;
    int m0 = (band ? (Tt - nc0 - CT) : nc0) * 64 + mi * 128;
    int n0 = band * 512 + ni * 256;
    gemm_tile(sent, emb, Wt, Uc, m0, n0, threadIdx.x, As, Bs, toks);
}

// ---------------------------------------------------------------------------
// K2: combo — blocks 0..127: LSTM chunk c0T; blocks 128..: GEMM for chunk
//   nc0. 143KB static LDS => 1 block/CU, no lstm/gemm co-residency.
//   No inter-block sync: lstm reads U from the PREVIOUS launch.
// ---------------------------------------------------------------------------
__global__ __launch_bounds__(512) void k_combo(const int* __restrict__ sent,
                                               const float* __restrict__ emb,
                                               const float* __restrict__ Wt,
                                               float* __restrict__ Uc,
                                               const float* __restrict__ Whh_f,
                                               const float* __restrict__ Whh_b,
                                               const float* __restrict__ bih_f,
                                               const float* __restrict__ bhh_f,
                                               const float* __restrict__ bih_b,
                                               const float* __restrict__ bhh_b,
                                               const float* __restrict__ h0,
                                               const float* __restrict__ c0,
                                               const float* __restrict__ Wout,
                                               float* __restrict__ hst,
                                               float* __restrict__ cst,
                                               float* __restrict__ pf,
                                               int c0T, int first, int nc0) {
    __shared__ float smem[35840];          // 143,360 B: CU-exclusive
    int bid = blockIdx.x;
    if (bid < 128) {
        int b = bid & 63, d = bid >> 6;
        lstm_chunk(Uc, d ? Whh_b : Whh_f, d ? bih_b : bih_f, d ? bhh_b : bhh_f,
                   h0, c0, Wout, hst, cst, pf, b, d, c0T, CTC, first, 1,
                   threadIdx.x, smem, smem + 128, smem + 640);
    } else {
        int gid = bid - 128;
        int band = gid / CTC, rem = gid % CTC;
        int ni = rem & 1, mi = rem >> 1;
        int m0 = (band ? (Tt - nc0 - CTC) : nc0) * 64 + mi * 128;
        int n0 = band * 512 + ni * 256;
        gemm_tile(sent, emb, Wt, Uc, m0, n0, threadIdx.x,
                  smem, smem + 2048, (int*)(smem + 6144));
    }
}

// ---------------------------------------------------------------------------
// fallback kernels (small ws): r14 serial path.
// ---------------------------------------------------------------------------
__global__ __launch_bounds__(256, 2) void k_gemm3(const int* __restrict__ sent,
                                                  const float* __restrict__ emb,
                                                  const float* __restrict__ Wt,
                                                  float* __restrict__ Uc,
                                                  int c0T, int CT) {
    __shared__ float As[2048];
    __shared__ float Bs[4096];
    __shared__ int   toks[128];
    int dz = blockIdx.z;
    int m0 = blockIdx.y * 128;
    int tid = threadIdx.x;
    if (tid < 128) {
        int m = m0 + tid;
        int it = m >> 6, b = m & 63;
        int t = dz ? (Tt - 1 - (c0T + it)) : (c0T + it);
        toks[tid] = sent[b * Tt + t];
    }
    __syncthreads();
    int ty = tid >> 4, tx = tid & 15;
    int am = tid & 127, ak4 = tid >> 7;
    int brow = tid >> 5, bc4 = tid & 31;
    int n0 = blockIdx.x * 256 + dz * G4;
    const float* aptr = emb + (size_t)toks[am] * Ee + ak4 * 4;
    const float* bptr = Wt + (size_t)brow * 1024 + n0 + bc4 * 4;
    float acc[8][16];
#pragma unroll
    for (int i = 0; i < 8; ++i)
#pragma unroll
        for (int j = 0; j < 16; ++j) acc[i][j] = 0.f;
    float4 av  = *(const float4*)(aptr);
    float4 bv0 = *(const float4*)(bptr);
    float4 bv1 = *(const float4*)(bptr + 128);
    const int NK = Ee / 8;
    for (int k = 0; k < NK; ++k) {
        int cur = k & 1;
        As[cur * 1024 + (ak4 * 4 + 0) * 128 + am] = av.x;
        As[cur * 1024 + (ak4 * 4 + 1) * 128 + am] = av.y;
        As[cur * 1024 + (ak4 * 4 + 2) * 128 + am] = av.z;
        As[cur * 1024 + (ak4 * 4 + 3) * 128 + am] = av.w;
        *(float4*)&Bs[cur * 2048 + brow * 256 + bc4 * 4]       = bv0;
        *(float4*)&Bs[cur * 2048 + brow * 256 + 128 + bc4 * 4] = bv1;
        __syncthreads();
        if (k + 1 < NK) {
            int kc = (k + 1) * 8;
            av  = *(const float4*)(aptr + kc);
            bv0 = *(const float4*)(bptr + (size_t)kc * 1024);
            bv1 = *(const float4*)(bptr + (size_t)kc * 1024 + 128);
        }
#pragma unroll
        for (int kk = 0; kk < 8; ++kk) {
            float a_[8], b_[16];
            *(float4*)&a_[0] = *(const float4*)&As[cur * 1024 + kk * 128 + ty * 8];
            *(float4*)&a_[4] = *(const float4*)&As[cur * 1024 + kk * 128 + ty * 8 + 4];
#pragma unroll
            for (int q = 0; q < 4; ++q)
                *(float4*)&b_[4 * q] =
                    *(const float4*)&Bs[cur * 2048 + kk * 256 + tx * 4 + 64 * q];
#pragma unroll
            for (int i = 0; i < 8; ++i)
#pragma unroll
                for (int j = 0; j < 16; ++j)
                    acc[i][j] = fmaf(a_[i], b_[j], acc[i][j]);
        }
    }
    float* base = Uc + (size_t)dz * ((size_t)CT * Bb * G4);
    int ncol = blockIdx.x * 256;
#pragma unroll
    for (int i = 0; i < 8; ++i) {
        float* dst = base + (size_t)(m0 + ty * 8 + i) * G4 + ncol + tx * 4;
#pragma unroll
        for (int q = 0; q < 4; ++q)
            *(float4*)(dst + 64 * q) = make_float4(acc[i][4 * q], acc[i][4 * q + 1],
                                                   acc[i][4 * q + 2], acc[i][4 * q + 3]);
    }
}

__global__ __launch_bounds__(512, 2) void k_lstm2(const float* __restrict__ Uc,
                                                  const float* __restrict__ Whh_f,
                                                  const float* __restrict__ Whh_b,
                                                  const float* __restrict__ bih_f,
                                                  const float* __restrict__ bhh_f,
                                                  const float* __restrict__ bih_b,
                                                  const float* __restrict__ bhh_b,
                                                  const float* __restrict__ h0,
                                                  const float* __restrict__ c0,
                                                  const float* __restrict__ Wout,
                                                  float* __restrict__ hst,
                                                  float* __restrict__ cst,
                                                  float* __restrict__ pf,
                                                  int c0T, int CT, int first) {
    __shared__ float smem[5464];
    int b = blockIdx.x & 63, d = blockIdx.x >> 6;
    lstm_chunk(Uc, d ? Whh_b : Whh_f, d ? bih_b : bih_f, d ? bhh_b : bhh_f,
               h0, c0, Wout, hst, cst, pf, b, d, c0T, CT, first, 0,
               threadIdx.x, smem, smem + 128, smem + 640);
}

// ---------------------------------------------------------------------------
// K3: Viterbi — single-round step: 24 parallel shfl broadcasts (bpermute,
//   the r16-proven primitive; NOT readlane) + depth-5 in-register first-max
//   tree (ties -> lower prev == jnp.argmax). No half-merge round. Feat read
//   hoisted to the top of each iteration. Staging/terminal/backtrace = r16.
// ---------------------------------------------------------------------------
#define CMB(av, ai, bv_, bi_, ov, oi)                         \
    { bool g = (bv_) > (av); ov = g ? (bv_) : (av); oi = g ? (bi_) : (ai); }

__global__ __launch_bounds__(64) void k_viterbi(const float* __restrict__ pf,
                                                const float* __restrict__ bout,
                                                const float* __restrict__ trans,
                                                float* __restrict__ out) {
    __shared__ unsigned char bptr[Tt * Kk];
    __shared__ float fsh[2][64][25];
    __shared__ float tsh[Kk];
    __shared__ unsigned char path[Tt];

    int lane = threadIdx.x;
    int b    = blockIdx.x;
    int n    = (lane < Kk) ? lane : 0;     // owned tag (clamped for idle lanes)

    float tr[Kk];
#pragma unroll
    for (int p = 0; p < Kk; ++p) tr[p] = trans[n * Kk + p];   // [next=n][prev]
    float bo = bout[n];

    float v = (lane == 0) ? 0.f : NEGf;    // lane p holds v[p] (p<24)

    const float* p0 = pf + (size_t)b * Tt * Kk;
    const float* p1 = pf + (size_t)(Bb + b) * Tt * Kk;

    float4 r0[6], r1[6];
#pragma unroll
    for (int j = 0; j < 6; ++j) {
        int f = 4 * (lane + 64 * j);
        r0[j] = *(const float4*)(p0 + f);
        r1[j] = *(const float4*)(p1 + f);
    }
#pragma unroll
    for (int j = 0; j < 6; ++j) {
        int f = 4 * (lane + 64 * j);
        int s = f / 24, k = f - 24 * s;
        fsh[0][s][k + 0] = r0[j].x + r1[j].x;
        fsh[0][s][k + 1] = r0[j].y + r1[j].y;
        fsh[0][s][k + 2] = r0[j].z + r1[j].z;
        fsh[0][s][k + 3] = r0[j].w + r1[j].w;
    }

    for (int c = 0; c < 16; ++c) {
        int cur = c & 1;
        if (c + 1 < 16) {
            const float* q0 = p0 + (c + 1) * 1536;
            const float* q1 = p1 + (c + 1) * 1536;
#pragma unroll
            for (int j = 0; j < 6; ++j) {
                int f = 4 * (lane + 64 * j);
                r0[j] = *(const float4*)(q0 + f);
                r1[j] = *(const float4*)(q1 + f);
            }
        }

        for (int s = 0; s < 64; ++s) {
            int t = c * 64 + s;
            float feat = fsh[cur][s][n] + bo;          // off the chain tail

            // one parallel broadcast round: 24 independent shfl (bpermute)
            float cand[Kk];
#pragma unroll
            for (int p = 0; p < Kk; ++p) cand[p] = __shfl(v, p) + tr[p];

            // 24 -> 12 -> 6 -> 3 -> 1 first-max tournament (ties: lower p)
            float l1v[12]; int l1i[12];
#pragma unroll
            for (int j = 0; j < 12; ++j)
                CMB(cand[2 * j], 2 * j, cand[2 * j + 1], 2 * j + 1, l1v[j], l1i[j]);
            float l2v[6]; int l2i[6];
#pragma unroll
            for (int j = 0; j < 6; ++j)
                CMB(l1v[2 * j], l1i[2 * j], l1v[2 * j + 1], l1i[2 * j + 1],
                    l2v[j], l2i[j]);
            float l3v[3]; int l3i[3];
#pragma unroll
            for (int j = 0; j < 3; ++j)
                CMB(l2v[2 * j], l2i[2 * j], l2v[2 * j + 1], l2i[2 * j + 1],
                    l3v[j], l3i[j]);
            float mv; int mi;
            CMB(l3v[0], l3i[0], l3v[1], l3i[1], mv, mi);
            float best; int bp;
            CMB(mv, mi, l3v[2], l3i[2], best, bp);

            v = best + feat;
            if (lane < Kk) bptr[t * Kk + lane] = (unsigned char)bp;
        }

        if (c + 1 < 16) {
#pragma unroll
            for (int j = 0; j < 6; ++j) {
                int f = 4 * (lane + 64 * j);
                int s = f / 24, k = f - 24 * s;
                fsh[cur ^ 1][s][k + 0] = r0[j].x + r1[j].x;
                fsh[cur ^ 1][s][k + 1] = r0[j].y + r1[j].y;
                fsh[cur ^ 1][s][k + 2] = r0[j].z + r1[j].z;
                fsh[cur ^ 1][s][k + 3] = r0[j].w + r1[j].w;
            }
        }
    }

    if (lane < Kk) tsh[n] = v + trans[1 * Kk + n];   // STOP=1
    __syncthreads();

    if (lane == 0) {
        float bestv = tsh[0];
        int tag = 0;
        for (int q = 1; q < Kk; ++q)
            if (tsh[q] > bestv) { bestv = tsh[q]; tag = q; }
        out[b] = bestv;
        for (int t = Tt - 1; t >= 1; --t) {
            path[t] = (unsigned char)tag;
            tag = bptr[t * Kk + tag];
        }
        path[0] = (unsigned char)tag;
    }
    __syncthreads();

    float* otag = out + Bb + (size_t)b * Tt;
    for (int t = lane; t < Tt; t += 64) otag[t] = (float)path[t];
}

// ---------------------------------------------------------------------------
// host launcher
// ---------------------------------------------------------------------------
extern "C" void kernel_launch(void* const* d_in, const int* in_sizes, int n_in,
                              void* d_out, int out_size, void* d_ws, size_t ws_size,
                              hipStream_t stream) {
    const int*   sent  = (const int*)d_in[0];
    const float* emb   = (const float*)d_in[2];
    const float* Wih_f = (const float*)d_in[3];
    const float* Whh_f = (const float*)d_in[4];
    const float* bih_f = (const float*)d_in[5];
    const float* bhh_f = (const float*)d_in[6];
    const float* Wih_b = (const float*)d_in[7];
    const float* Whh_b = (const float*)d_in[8];
    const float* bih_b = (const float*)d_in[9];
    const float* bhh_b = (const float*)d_in[10];
    const float* h0    = (const float*)d_in[11];
    const float* c0    = (const float*)d_in[12];
    const float* Wout  = (const float*)d_in[13];
    const float* bout  = (const float*)d_in[14];
    const float* trans = (const float*)d_in[15];

    float* ws  = (float*)d_ws;
    float* Wt  = ws;                       //   204,800 f
    float* pf  = Wt + 204800;              // 3,145,728 f
    float* hst = pf + 3145728;             //    16,384 f
    float* cst = hst + 16384;              //    16,384 f
    float* Uc  = cst + 16384;

    const size_t fixedf = 204800 + 3145728 + 16384 + 16384;
    size_t needU = (size_t)2 * Tt * Bb * G4;
    int unified = ((fixedf + needU) * 4 <= ws_size);

    k_wt<<<(Ee * 1024 + 255) / 256, 256, 0, stream>>>(Wih_f, Wih_b, Wt);

    if (unified) {
        const int NC = Tt / CTC;           // 8
        k_gpro<<<2 * CTC, 256, 0, stream>>>(sent, emb, Wt, Uc, 0, CTC);
        for (int c = 0; c < NC; ++c) {
            int hasg = (c + 1 < NC);
            int grid = 128 + (hasg ? 2 * CTC : 0);
            k_combo<<<grid, 512, 0, stream>>>(sent, emb, Wt, Uc,
                                              Whh_f, Whh_b, bih_f, bhh_f,
                                              bih_b, bhh_b, h0, c0, Wout,
                                              hst, cst, pf,
                                              c * CTC, c == 0, (c + 1) * CTC);
        }
    } else {
        int CT = 64;
        const int cands[3] = {512, 256, 128};
        for (int ci = 0; ci < 3; ++ci)
            if ((fixedf + (size_t)2 * cands[ci] * Bb * G4) * 4 <= ws_size) {
                CT = cands[ci]; break;
            }
        int NC = Tt / CT;
        for (int cix = 0; cix < NC; ++cix) {
            k_gemm3<<<dim3(2, CT * 64 / 128, 2), 256, 0, stream>>>(
                sent, emb, Wt, Uc, cix * CT, CT);
            k_lstm2<<<128, 512, 0, stream>>>(Uc, Whh_f, Whh_b, bih_f, bhh_f,
                                             bih_b, bhh_b, h0, c0, Wout,
                                             hst, cst, pf, cix * CT, CT,
                                             cix == 0);
        }
    }

    k_viterbi<<<Bb, 64, 0, stream>>>(pf, bout, trans, (float*)d_out);
}

// Round 20
// 1391.687 us; speedup vs baseline: 1.3484x; 1.3484x over previous
//
#include <hip/hip_runtime.h>
#include <math.h>

#define Ee   200
#define Hh   128
#define G4   512          // 4*H
#define Kk   24
#define Bb   64
#define Tt   1024
#define HIDd 256
#define NEGf (-10000.0f)
#define PSTR 9            // partial-sum LDS stride (odd -> conflict-free)
#define CTC  128          // combo chunk length (8 chunks)

// ---------------------------------------------------------------------------
// K0: Wt[k][n] (k<200, n<1024): n<512 -> W_ih_f[n][k], else W_ih_b[n-512][k]
// ---------------------------------------------------------------------------
__global__ __launch_bounds__(256) void k_wt(const float* __restrict__ Wf,
                                            const float* __restrict__ Wb,
                                            float* __restrict__ Wt) {
    int idx = blockIdx.x * 256 + threadIdx.x;
    if (idx >= Ee * 1024) return;
    int k = idx >> 10, n = idx & 1023;
    Wt[idx] = (n < G4) ? Wf[n * Ee + k] : Wb[(n - G4) * Ee + k];
}

// ---------------------------------------------------------------------------
// GEMM tile body (proven r14/r16): BM=128 x BN=256, K=200, dbuf LDS,
//   one barrier per K-iter. tid<256 active; extra threads only hit barriers.
// ---------------------------------------------------------------------------
__device__ __forceinline__ void gemm_tile(const int* __restrict__ sent,
                                          const float* __restrict__ emb,
                                          const float* __restrict__ Wt,
                                          float* __restrict__ Uc,
                                          int m0, int n0, int tid,
                                          float* As, float* Bs, int* toks) {
    bool act = (tid < 256);
    int ty = (tid & 255) >> 4, tx = tid & 15;

    if (tid < 128) {
        int m = m0 + tid;
        toks[tid] = sent[(m & 63) * Tt + (m >> 6)];
    }
    __syncthreads();

    int am = tid & 127, ak4 = (tid >> 7) & 1;
    int brow = (tid >> 5) & 7, bc4 = tid & 31;

    const float* aptr = emb;
    const float* bptr = Wt;
    float4 av = make_float4(0, 0, 0, 0), bv0 = av, bv1 = av;
    float acc[8][16];
    if (act) {
        aptr = emb + (size_t)toks[am] * Ee + ak4 * 4;
        bptr = Wt + (size_t)brow * 1024 + n0 + bc4 * 4;
#pragma unroll
        for (int i = 0; i < 8; ++i)
#pragma unroll
            for (int j = 0; j < 16; ++j) acc[i][j] = 0.f;
        av  = *(const float4*)(aptr);
        bv0 = *(const float4*)(bptr);
        bv1 = *(const float4*)(bptr + 128);
    }

    const int NK = Ee / 8;                 // 25
    for (int k = 0; k < NK; ++k) {
        int cur = k & 1;
        if (act) {
            As[cur * 1024 + (ak4 * 4 + 0) * 128 + am] = av.x;
            As[cur * 1024 + (ak4 * 4 + 1) * 128 + am] = av.y;
            As[cur * 1024 + (ak4 * 4 + 2) * 128 + am] = av.z;
            As[cur * 1024 + (ak4 * 4 + 3) * 128 + am] = av.w;
            *(float4*)&Bs[cur * 2048 + brow * 256 + bc4 * 4]       = bv0;
            *(float4*)&Bs[cur * 2048 + brow * 256 + 128 + bc4 * 4] = bv1;
        }
        __syncthreads();                   // only barrier this iter

        if (act && k + 1 < NK) {
            int kc = (k + 1) * 8;
            av  = *(const float4*)(aptr + kc);
            bv0 = *(const float4*)(bptr + (size_t)kc * 1024);
            bv1 = *(const float4*)(bptr + (size_t)kc * 1024 + 128);
        }

        if (act) {
#pragma unroll
            for (int kk = 0; kk < 8; ++kk) {
                float a_[8], b_[16];
                *(float4*)&a_[0] = *(const float4*)&As[cur * 1024 + kk * 128 + ty * 8];
                *(float4*)&a_[4] = *(const float4*)&As[cur * 1024 + kk * 128 + ty * 8 + 4];
#pragma unroll
                for (int q = 0; q < 4; ++q)
                    *(float4*)&b_[4 * q] =
                        *(const float4*)&Bs[cur * 2048 + kk * 256 + tx * 4 + 64 * q];
#pragma unroll
                for (int i = 0; i < 8; ++i)
#pragma unroll
                    for (int j = 0; j < 16; ++j)
                        acc[i][j] = fmaf(a_[i], b_[j], acc[i][j]);
            }
        }
    }

    if (act) {
        int dd = n0 >> 9, ncol = n0 & 511;
        float* base = Uc + (size_t)dd * ((size_t)Tt * Bb * G4);
#pragma unroll
        for (int i = 0; i < 8; ++i) {
            float* dst = base + (size_t)(m0 + ty * 8 + i) * G4 + ncol + tx * 4;
#pragma unroll
            for (int q = 0; q < 4; ++q)
                *(float4*)(dst + 64 * q) =
                    make_float4(acc[i][4 * q], acc[i][4 * q + 1],
                                acc[i][4 * q + 2], acc[i][4 * q + 3]);
        }
    }
}

// ---------------------------------------------------------------------------
// LSTM chunk body — EXACT v2 math (proven 920us, conflicts=0), chunk-aware
//   unified indexing: u0 = d ? (Tt-1-c0T) : c0T.
// ---------------------------------------------------------------------------
__device__ __forceinline__ void lstm_chunk(const float* __restrict__ Uc,
                                           const float* __restrict__ Whh,
                                           const float* __restrict__ bih,
                                           const float* __restrict__ bhh,
                                           const float* __restrict__ h0v,
                                           const float* __restrict__ c0v,
                                           const float* __restrict__ Wout,
                                           float* __restrict__ hst,
                                           float* __restrict__ cst,
                                           float* __restrict__ pf,
                                           int b, int d, int c0T, int CT,
                                           int first, int unified, int tid,
                                           float* hsh, float* gsh, float* ps) {
    int lane = tid & 63, wv = tid >> 6;

    float bias = bih[tid] + bhh[tid];

    float w[8][16];
#pragma unroll
    for (int ri = 0; ri < 8; ++ri) {
        const float* wr = Whh + (size_t)(ri * 64 + lane) * Hh + wv * 16;
#pragma unroll
        for (int c4 = 0; c4 < 4; ++c4)
            *(float4*)&w[ri][c4 * 4] = *(const float4*)(wr + c4 * 4);
    }
    float wt[16];
    if (lane < Kk) {
        const float* wr = Wout + (size_t)lane * HIDd + d * Hh + wv * 16;
#pragma unroll
        for (int c4 = 0; c4 < 4; ++c4)
            *(float4*)&wt[c4 * 4] = *(const float4*)(wr + c4 * 4);
    }

    float cc = 0.f;
    if (tid < Hh) {
        int si = (d * Bb + b) * Hh + tid;
        hsh[tid] = first ? h0v[si] : hst[si];
        cc       = first ? c0v[si] : cst[si];
    }
    __syncthreads();

    const float* Ub = Uc + (size_t)d * ((size_t)(unified ? Tt : CT) * Bb * G4);
    int u0 = unified ? (d ? (Tt - 1 - c0T) : c0T) : 0;
    int us = unified ? (d ? -1 : 1) : 1;

    float ucur = Ub[(size_t)u0 * (Bb * G4) + b * G4 + tid];
    float unext = 0.f;

    for (int i = 0; i <= CT; ++i) {
        int last = (i == CT);
        float hv[16];
        *(float4*)&hv[0]  = *(const float4*)&hsh[wv * 16];
        *(float4*)&hv[4]  = *(const float4*)&hsh[wv * 16 + 4];
        *(float4*)&hv[8]  = *(const float4*)&hsh[wv * 16 + 8];
        *(float4*)&hv[12] = *(const float4*)&hsh[wv * 16 + 12];

        if (lane < Kk) {
            float s = 0.f;
#pragma unroll
            for (int c = 0; c < 16; ++c) s = fmaf(wt[c], hv[c], s);
            ps[(G4 + lane) * PSTR + wv] = s;
        }
        if (!last) {
#pragma unroll
            for (int ri = 0; ri < 8; ++ri) {
                float s = 0.f;
#pragma unroll
                for (int c = 0; c < 16; ++c) s = fmaf(w[ri][c], hv[c], s);
                ps[(ri * 64 + lane) * PSTR + wv] = s;
            }
            if (i + 1 < CT)
                unext = Ub[(size_t)(u0 + (i + 1) * us) * (Bb * G4) + b * G4 + tid];
        }
        __syncthreads();

        if (!last) {
            const float* pr = ps + (size_t)tid * PSTR;
            float s = ((pr[0] + pr[1]) + (pr[2] + pr[3])) +
                      ((pr[4] + pr[5]) + (pr[6] + pr[7]));
            s += ucur + bias;
            int gt = tid >> 7;                      // 0:i 1:f 2:g 3:o
            gsh[tid] = (gt == 2) ? tanhf(s) : 1.f / (1.f + expf(-s));
        }
        __syncthreads();

        if (!last && tid < Hh) {
            float gi = gsh[tid], gf = gsh[Hh + tid];
            float gg = gsh[2 * Hh + tid], go = gsh[3 * Hh + tid];
            cc = gf * cc + gi * gg;
            hsh[tid] = go * tanhf(cc);
        }
        if (tid >= 128 && tid < 128 + Kk && i >= 1) {
            int k = tid - 128;
            const float* pr = ps + (size_t)(G4 + k) * PSTR;
            float s = ((pr[0] + pr[1]) + (pr[2] + pr[3])) +
                      ((pr[4] + pr[5]) + (pr[6] + pr[7]));
            int tp = c0T + i - 1;
            int tg = d ? (Tt - 1 - tp) : tp;
            pf[((size_t)(d * Bb + b) * Tt + tg) * Kk + k] = s;
        }
        __syncthreads();
        ucur = unext;
    }

    if (tid < Hh) {
        int si = (d * Bb + b) * Hh + tid;
        hst[si] = hsh[tid];
        cst[si] = cc;
    }
}

// ---------------------------------------------------------------------------
// K1a: prologue GEMM for chunk 0 — small LDS (2 blocks/CU), full chip.
// ---------------------------------------------------------------------------
__global__ __launch_bounds__(256, 2) void k_gpro(const int* __restrict__ sent,
                                                 const float* __restrict__ emb,
                                                 const float* __restrict__ Wt,
                                                 float* __restrict__ Uc,
                                                 int nc0, int CT) {
    __shared__ float As[2048];
    __shared__ float Bs[4096];
    __shared__ int   toks[128];
    int gid = blockIdx.x;
    int band = gid / CT, rem = gid % CT;
    int ni = rem & 1, mi = rem >> 1;
    int m0 = (band ? (Tt - nc0 - CT) : nc0) * 64 + mi * 128;
    int n0 = band * 512 + ni * 256;
    gemm_tile(sent, emb, Wt, Uc, m0, n0, threadIdx.x, As, Bs, toks);
}

// ---------------------------------------------------------------------------
// K2: combo — blocks 0..127: LSTM chunk c0T; blocks 128..: GEMM for chunk
//   nc0. 143KB static LDS => 1 block/CU, no lstm/gemm co-residency.
//   No inter-block sync: lstm reads U from the PREVIOUS launch.
// ---------------------------------------------------------------------------
__global__ __launch_bounds__(512) void k_combo(const int* __restrict__ sent,
                                               const float* __restrict__ emb,
                                               const float* __restrict__ Wt,
                                               float* __restrict__ Uc,
                                               const float* __restrict__ Whh_f,
                                               const float* __restrict__ Whh_b,
                                               const float* __restrict__ bih_f,
                                               const float* __restrict__ bhh_f,
                                               const float* __restrict__ bih_b,
                                               const float* __restrict__ bhh_b,
                                               const float* __restrict__ h0,
                                               const float* __restrict__ c0,
                                               const float* __restrict__ Wout,
                                               float* __restrict__ hst,
                                               float* __restrict__ cst,
                                               float* __restrict__ pf,
                                               int c0T, int first, int nc0) {
    __shared__ float smem[35840];          // 143,360 B: CU-exclusive
    int bid = blockIdx.x;
    if (bid < 128) {
        int b = bid & 63, d = bid >> 6;
        lstm_chunk(Uc, d ? Whh_b : Whh_f, d ? bih_b : bih_f, d ? bhh_b : bhh_f,
                   h0, c0, Wout, hst, cst, pf, b, d, c0T, CTC, first, 1,
                   threadIdx.x, smem, smem + 128, smem + 640);
    } else {
        int gid = bid - 128;
        int band = gid / CTC, rem = gid % CTC;
        int ni = rem & 1, mi = rem >> 1;
        int m0 = (band ? (Tt - nc0 - CTC) : nc0) * 64 + mi * 128;
        int n0 = band * 512 + ni * 256;
        gemm_tile(sent, emb, Wt, Uc, m0, n0, threadIdx.x,
                  smem, smem + 2048, (int*)(smem + 6144));
    }
}

// ---------------------------------------------------------------------------
// fallback kernels (small ws): r14 serial path.
// ---------------------------------------------------------------------------
__global__ __launch_bounds__(256, 2) void k_gemm3(const int* __restrict__ sent,
                                                  const float* __restrict__ emb,
                                                  const float* __restrict__ Wt,
                                                  float* __restrict__ Uc,
                                                  int c0T, int CT) {
    __shared__ float As[2048];
    __shared__ float Bs[4096];
    __shared__ int   toks[128];
    int dz = blockIdx.z;
    int m0 = blockIdx.y * 128;
    int tid = threadIdx.x;
    if (tid < 128) {
        int m = m0 + tid;
        int it = m >> 6, b = m & 63;
        int t = dz ? (Tt - 1 - (c0T + it)) : (c0T + it);
        toks[tid] = sent[b * Tt + t];
    }
    __syncthreads();
    int ty = tid >> 4, tx = tid & 15;
    int am = tid & 127, ak4 = tid >> 7;
    int brow = tid >> 5, bc4 = tid & 31;
    int n0 = blockIdx.x * 256 + dz * G4;
    const float* aptr = emb + (size_t)toks[am] * Ee + ak4 * 4;
    const float* bptr = Wt + (size_t)brow * 1024 + n0 + bc4 * 4;
    float acc[8][16];
#pragma unroll
    for (int i = 0; i < 8; ++i)
#pragma unroll
        for (int j = 0; j < 16; ++j) acc[i][j] = 0.f;
    float4 av  = *(const float4*)(aptr);
    float4 bv0 = *(const float4*)(bptr);
    float4 bv1 = *(const float4*)(bptr + 128);
    const int NK = Ee / 8;
    for (int k = 0; k < NK; ++k) {
        int cur = k & 1;
        As[cur * 1024 + (ak4 * 4 + 0) * 128 + am] = av.x;
        As[cur * 1024 + (ak4 * 4 + 1) * 128 + am] = av.y;
        As[cur * 1024 + (ak4 * 4 + 2) * 128 + am] = av.z;
        As[cur * 1024 + (ak4 * 4 + 3) * 128 + am] = av.w;
        *(float4*)&Bs[cur * 2048 + brow * 256 + bc4 * 4]       = bv0;
        *(float4*)&Bs[cur * 2048 + brow * 256 + 128 + bc4 * 4] = bv1;
        __syncthreads();
        if (k + 1 < NK) {
            int kc = (k + 1) * 8;
            av  = *(const float4*)(aptr + kc);
            bv0 = *(const float4*)(bptr + (size_t)kc * 1024);
            bv1 = *(const float4*)(bptr + (size_t)kc * 1024 + 128);
        }
#pragma unroll
        for (int kk = 0; kk < 8; ++kk) {
            float a_[8], b_[16];
            *(float4*)&a_[0] = *(const float4*)&As[cur * 1024 + kk * 128 + ty * 8];
            *(float4*)&a_[4] = *(const float4*)&As[cur * 1024 + kk * 128 + ty * 8 + 4];
#pragma unroll
            for (int q = 0; q < 4; ++q)
                *(float4*)&b_[4 * q] =
                    *(const float4*)&Bs[cur * 2048 + kk * 256 + tx * 4 + 64 * q];
#pragma unroll
            for (int i = 0; i < 8; ++i)
#pragma unroll
                for (int j = 0; j < 16; ++j)
                    acc[i][j] = fmaf(a_[i], b_[j], acc[i][j]);
        }
    }
    float* base = Uc + (size_t)dz * ((size_t)CT * Bb * G4);
    int ncol = blockIdx.x * 256;
#pragma unroll
    for (int i = 0; i < 8; ++i) {
        float* dst = base + (size_t)(m0 + ty * 8 + i) * G4 + ncol + tx * 4;
#pragma unroll
        for (int q = 0; q < 4; ++q)
            *(float4*)(dst + 64 * q) = make_float4(acc[i][4 * q], acc[i][4 * q + 1],
                                                   acc[i][4 * q + 2], acc[i][4 * q + 3]);
    }
}

__global__ __launch_bounds__(512, 2) void k_lstm2(const float* __restrict__ Uc,
                                                  const float* __restrict__ Whh_f,
                                                  const float* __restrict__ Whh_b,
                                                  const float* __restrict__ bih_f,
                                                  const float* __restrict__ bhh_f,
                                                  const float* __restrict__ bih_b,
                                                  const float* __restrict__ bhh_b,
                                                  const float* __restrict__ h0,
                                                  const float* __restrict__ c0,
                                                  const float* __restrict__ Wout,
                                                  float* __restrict__ hst,
                                                  float* __restrict__ cst,
                                                  float* __restrict__ pf,
                                                  int c0T, int CT, int first) {
    __shared__ float smem[5464];
    int b = blockIdx.x & 63, d = blockIdx.x >> 6;
    lstm_chunk(Uc, d ? Whh_b : Whh_f, d ? bih_b : bih_f, d ? bhh_b : bhh_f,
               h0, c0, Wout, hst, cst, pf, b, d, c0T, CT, first, 0,
               threadIdx.x, smem, smem + 128, smem + 640);
}

// ---------------------------------------------------------------------------
// K3: Viterbi — EXACT r16 version (proven 343us): tree-argmax, two lane
//   halves, 64-step LDS-staged feats. Minimal-bpermute step (12+2).
// ---------------------------------------------------------------------------
#define CMB(av, ai, bv_, bi_, ov, oi)                         \
    { bool g = (bv_) > (av); ov = g ? (bv_) : (av); oi = g ? (bi_) : (ai); }

__global__ __launch_bounds__(64) void k_viterbi(const float* __restrict__ pf,
                                                const float* __restrict__ bout,
                                                const float* __restrict__ trans,
                                                float* __restrict__ out) {
    __shared__ unsigned char bptr[Tt * Kk];
    __shared__ float fsh[2][64][25];
    __shared__ float tsh[Kk];
    __shared__ unsigned char path[Tt];

    int lane = threadIdx.x;
    int b    = blockIdx.x;
    int half   = (lane >= Kk) ? 1 : 0;
    int n      = half ? (lane - Kk) : lane;
    int active = (lane < 2 * Kk);

    float tr[12];
    float bo = 0.f;
    if (active) {
#pragma unroll
        for (int j = 0; j < 12; ++j) tr[j] = trans[n * Kk + half * 12 + j];
        bo = bout[n];
    }
    float v = (lane == 0) ? 0.f : NEGf;   // START=0

    const float* p0 = pf + (size_t)b * Tt * Kk;
    const float* p1 = pf + (size_t)(Bb + b) * Tt * Kk;

    float4 r0[6], r1[6];
#pragma unroll
    for (int j = 0; j < 6; ++j) {
        int f = 4 * (lane + 64 * j);
        r0[j] = *(const float4*)(p0 + f);
        r1[j] = *(const float4*)(p1 + f);
    }
#pragma unroll
    for (int j = 0; j < 6; ++j) {
        int f = 4 * (lane + 64 * j);
        int s = f / 24, k = f - 24 * s;
        fsh[0][s][k + 0] = r0[j].x + r1[j].x;
        fsh[0][s][k + 1] = r0[j].y + r1[j].y;
        fsh[0][s][k + 2] = r0[j].z + r1[j].z;
        fsh[0][s][k + 3] = r0[j].w + r1[j].w;
    }

    for (int c = 0; c < 16; ++c) {
        int cur = c & 1;
        if (c + 1 < 16) {
            const float* q0 = p0 + (c + 1) * 1536;
            const float* q1 = p1 + (c + 1) * 1536;
#pragma unroll
            for (int j = 0; j < 6; ++j) {
                int f = 4 * (lane + 64 * j);
                r0[j] = *(const float4*)(q0 + f);
                r1[j] = *(const float4*)(q1 + f);
            }
        }

        for (int s = 0; s < 64; ++s) {
            int t = c * 64 + s;
            if (active) {
                int pb = half * 12;
                float sc[12];
#pragma unroll
                for (int j = 0; j < 12; ++j) sc[j] = __shfl(v, pb + j) + tr[j];

                float l1v[6]; int l1i[6];
#pragma unroll
                for (int j = 0; j < 6; ++j)
                    CMB(sc[2 * j], 2 * j, sc[2 * j + 1], 2 * j + 1, l1v[j], l1i[j]);
                float l2v[3]; int l2i[3];
#pragma unroll
                for (int j = 0; j < 3; ++j)
                    CMB(l1v[2 * j], l1i[2 * j], l1v[2 * j + 1], l1i[2 * j + 1],
                        l2v[j], l2i[j]);
                float dv; int di;
                CMB(l2v[0], l2i[0], l2v[1], l2i[1], dv, di);
                float best; int bp;
                CMB(dv, di, l2v[2], l2i[2], best, bp);
                bp += pb;

                float ob  = __shfl(best, n + Kk);
                int   obp = __shfl(bp,   n + Kk);
                if (half == 0) {
                    if (ob > best) { best = ob; bp = obp; }
                    v = best + fsh[cur][s][n] + bo;
                    bptr[t * Kk + n] = (unsigned char)bp;
                }
            }
        }

        if (c + 1 < 16) {
#pragma unroll
            for (int j = 0; j < 6; ++j) {
                int f = 4 * (lane + 64 * j);
                int s = f / 24, k = f - 24 * s;
                fsh[cur ^ 1][s][k + 0] = r0[j].x + r1[j].x;
                fsh[cur ^ 1][s][k + 1] = r0[j].y + r1[j].y;
                fsh[cur ^ 1][s][k + 2] = r0[j].z + r1[j].z;
                fsh[cur ^ 1][s][k + 3] = r0[j].w + r1[j].w;
            }
        }
    }

    if (half == 0 && lane < Kk) tsh[n] = v + trans[1 * Kk + n];   // STOP=1
    __syncthreads();

    if (lane == 0) {
        float bestv = tsh[0];
        int tag = 0;
        for (int q = 1; q < Kk; ++q)
            if (tsh[q] > bestv) { bestv = tsh[q]; tag = q; }
        out[b] = bestv;
        for (int t = Tt - 1; t >= 1; --t) {
            path[t] = (unsigned char)tag;
            tag = bptr[t * Kk + tag];
        }
        path[0] = (unsigned char)tag;
    }
    __syncthreads();

    float* otag = out + Bb + (size_t)b * Tt;
    for (int t = lane; t < Tt; t += 64) otag[t] = (float)path[t];
}

// ---------------------------------------------------------------------------
// host launcher
// ---------------------------------------------------------------------------
extern "C" void kernel_launch(void* const* d_in, const int* in_sizes, int n_in,
                              void* d_out, int out_size, void* d_ws, size_t ws_size,
                              hipStream_t stream) {
    const int*   sent  = (const int*)d_in[0];
    const float* emb   = (const float*)d_in[2];
    const float* Wih_f = (const float*)d_in[3];
    const float* Whh_f = (const float*)d_in[4];
    const float* bih_f = (const float*)d_in[5];
    const float* bhh_f = (const float*)d_in[6];
    const float* Wih_b = (const float*)d_in[7];
    const float* Whh_b = (const float*)d_in[8];
    const float* bih_b = (const float*)d_in[9];
    const float* bhh_b = (const float*)d_in[10];
    const float* h0    = (const float*)d_in[11];
    const float* c0    = (const float*)d_in[12];
    const float* Wout  = (const float*)d_in[13];
    const float* bout  = (const float*)d_in[14];
    const float* trans = (const float*)d_in[15];

    float* ws  = (float*)d_ws;
    float* Wt  = ws;                       //   204,800 f
    float* pf  = Wt + 204800;              // 3,145,728 f
    float* hst = pf + 3145728;             //    16,384 f
    float* cst = hst + 16384;              //    16,384 f
    float* Uc  = cst + 16384;

    const size_t fixedf = 204800 + 3145728 + 16384 + 16384;
    size_t needU = (size_t)2 * Tt * Bb * G4;
    int unified = ((fixedf + needU) * 4 <= ws_size);

    k_wt<<<(Ee * 1024 + 255) / 256, 256, 0, stream>>>(Wih_f, Wih_b, Wt);

    if (unified) {
        const int NC = Tt / CTC;           // 8
        k_gpro<<<2 * CTC, 256, 0, stream>>>(sent, emb, Wt, Uc, 0, CTC);
        for (int c = 0; c < NC; ++c) {
            int hasg = (c + 1 < NC);
            int grid = 128 + (hasg ? 2 * CTC : 0);
            k_combo<<<grid, 512, 0, stream>>>(sent, emb, Wt, Uc,
                                              Whh_f, Whh_b, bih_f, bhh_f,
                                              bih_b, bhh_b, h0, c0, Wout,
                                              hst, cst, pf,
                                              c * CTC, c == 0, (c + 1) * CTC);
        }
    } else {
        int CT = 64;
        const int cands[3] = {512, 256, 128};
        for (int ci = 0; ci < 3; ++ci)
            if ((fixedf + (size_t)2 * cands[ci] * Bb * G4) * 4 <= ws_size) {
                CT = cands[ci]; break;
            }
        int NC = Tt / CT;
        for (int cix = 0; cix < NC; ++cix) {
            k_gemm3<<<dim3(2, CT * 64 / 128, 2), 256, 0, stream>>>(
                sent, emb, Wt, Uc, cix * CT, CT);
            k_lstm2<<<128, 512, 0, stream>>>(Uc, Whh_f, Whh_b, bih_f, bhh_f,
                                             bih_b, bhh_b, h0, c0, Wout,
                                             hst, cst, pf, cix * CT, CT,
                                             cix == 0);
        }
    }

    k_viterbi<<<Bb, 64, 0, stream>>>(pf, bout, trans, (float*)d_out);
}